// Round 6
// baseline (195.486 us; speedup 1.0000x reference)
//
#include <hip/hip_runtime.h>

#define NN 50000
#define NE 640000
#define NB 196  // ceil((NN+1)/256)

typedef __attribute__((ext_vector_type(8))) short s8v;
typedef __attribute__((ext_vector_type(4))) float f4v;

__device__ __forceinline__ unsigned short f2bf(float x) {  // RNE f32->bf16
  unsigned int u = __float_as_uint(x);
  return (unsigned short)((u + 0x7fffu + ((u >> 16) & 1u)) >> 16);
}
__device__ __forceinline__ float bfval(unsigned short h) {
  return __uint_as_float((unsigned int)h << 16);
}
__device__ __forceinline__ float2 bfpair(unsigned int u) {
  float2 r;
  r.x = __uint_as_float((u & 0xffffu) << 16);
  r.y = __uint_as_float(u & 0xffff0000u);
  return r;
}

// ---------------- CSR (dest-keyed) build ----------------

__global__ void count_kernel(const int* __restrict__ col, int* __restrict__ cnt, int n) {
  int i = blockIdx.x * blockDim.x + threadIdx.x;
  if (i < n) atomicAdd(&cnt[col[i]], 1);
}

// Fused hierarchical scan: block b re-reduces cnt[0..b*256) (L2-resident, ~1us),
// then in-block scan -> row_ptr + dis. Replaces 3 kernels.
__global__ __launch_bounds__(256) void rowptr_kernel(
    const int* __restrict__ cnt, int* __restrict__ row_ptr,
    float* __restrict__ dis, int n) {
  __shared__ int red[4];
  __shared__ int wsum[4];
  const int tid = threadIdx.x;
  const int b = blockIdx.x;
  const int t = b * 256 + tid;
  const int lane = tid & 63, w = tid >> 6;

  int pre = 0;
  for (int i = tid; i < b * 256; i += 256) pre += cnt[i];
#pragma unroll
  for (int off = 1; off < 64; off <<= 1) pre += __shfl_xor(pre, off);
  if (lane == 0) red[w] = pre;
  __syncthreads();
  const int preS = red[0] + red[1] + red[2] + red[3];

  int c = (t < n) ? cnt[t] : 0;
  int inc = c;
#pragma unroll
  for (int off = 1; off < 64; off <<= 1) {
    int u = __shfl_up(inc, off);
    if (lane >= off) inc += u;
  }
  if (lane == 63) wsum[w] = inc;
  __syncthreads();
  int wo = 0;
  for (int i = 0; i < w; ++i) wo += wsum[i];
  int excl = preS + wo + inc - c;
  if (t <= n) row_ptr[t] = excl;
  if (t < n) dis[t] = rsqrtf((float)(c + 1));
}

__global__ void fill_kernel(const int* __restrict__ row, const int* __restrict__ col,
                            const int* __restrict__ row_ptr, int* __restrict__ fillc,
                            int* __restrict__ csr, int n) {
  int i = blockIdx.x * blockDim.x + threadIdx.x;
  if (i < n) {
    int c = col[i];
    int p = row_ptr[c] + atomicAdd(&fillc[c], 1);
    csr[p] = row[i];
  }
}

// ---------------- W prep: transpose + split f32 -> bf16 hi/lo ----------------

__global__ __launch_bounds__(256) void wprep_kernel(
    const float* __restrict__ W1, const float* __restrict__ W2,
    unsigned short* __restrict__ wt1h, unsigned short* __restrict__ wt1l,
    unsigned short* __restrict__ wt2h, unsigned short* __restrict__ wt2l) {
  int idx = blockIdx.x * 256 + threadIdx.x;  // 0..24575
  if (idx < 16384) {
    int c = idx >> 7, k = idx & 127;
    float w = W1[k * 128 + c];
    unsigned short h = f2bf(w);
    wt1h[idx] = h;
    wt1l[idx] = f2bf(w - bfval(h));
  } else if (idx < 24576) {
    int i2 = idx - 16384;
    int c = i2 >> 7, k = i2 & 127;
    float w = W2[k * 64 + c];
    unsigned short h = f2bf(w);
    wt2h[i2] = h;
    wt2l[i2] = f2bf(w - bfval(h));
  }
}

// ---------------- MFMA GEMM with register-prefetch pipeline ----------------
// out[r][c] = dis[r] * sum_{k<128} A[r][k] * Wt[c][k]
// Tile kt+1 is loaded into registers BEFORE the MFMA of tile kt; the convert +
// LDS write happens after the post-MFMA barrier -> HBM latency hides under MFMA.

template <int NCOLS, bool ASPLIT, bool OUTBF16>
__global__ __launch_bounds__(256) void gemm_mfma_kernel(
    const void* __restrict__ Av, const unsigned short* __restrict__ Bth,
    const unsigned short* __restrict__ Btl, const float* __restrict__ dis,
    void* __restrict__ outv, int M) {
  constexpr int WCOL = NCOLS / 64;   // waves along cols
  constexpr int WROW = 4 / WCOL;     // waves along rows
  constexpr int BM = WROW * 32;      // block rows (64 or 128)
  constexpr int P = 40;              // LDS pitch in bf16 (16B-aligned, 2-way free)
  constexpr int NBIT = NCOLS * 4 / 256;  // B stage iters (2 or 1)

  __shared__ unsigned short Ah[BM][P];
  __shared__ unsigned short Al[ASPLIT ? BM : 1][ASPLIT ? P : 1];
  __shared__ unsigned short Bh[NCOLS][P];
  __shared__ unsigned short Bl[NCOLS][P];

  const int t = threadIdx.x;
  const int lane = t & 63;
  const int l15 = lane & 15;
  const int lg = lane >> 4;
  const int wv = t >> 6;
  const int wr = wv % WROW;
  const int wc = wv / WROW;
  const int rb = blockIdx.x * BM;

  // prefetch registers
  int4 pbh[NBIT], pbl[NBIT];
  float4 paf[2];  // ASPLIT
  int4 pai[2];    // !ASPLIT

  auto load_tile = [&](int kt) {
#pragma unroll
    for (int it = 0; it < NBIT; ++it) {
      int f = t + it * 256;
      int c = f >> 2, kq = f & 3;
      pbh[it] = *reinterpret_cast<const int4*>(&Bth[c * 128 + kt * 32 + kq * 8]);
      pbl[it] = *reinterpret_cast<const int4*>(&Btl[c * 128 + kt * 32 + kq * 8]);
    }
    if constexpr (ASPLIT) {
      const float* A = (const float*)Av;
#pragma unroll
      for (int j = 0; j < 2; ++j) {
        int f = t + j * 256;
        int r = f >> 3, kq = f & 7;
        paf[j] = make_float4(0.f, 0.f, 0.f, 0.f);
        if (rb + r < M)
          paf[j] = *reinterpret_cast<const float4*>(&A[(size_t)(rb + r) * 128 + kt * 32 + kq * 4]);
      }
    } else {
      const unsigned short* A = (const unsigned short*)Av;
#pragma unroll
      for (int j = 0; j < 2; ++j) {
        int f = t + j * 256;
        int r = f >> 2, kq = f & 3;
        pai[j] = make_int4(0, 0, 0, 0);
        if (rb + r < M)
          pai[j] = *reinterpret_cast<const int4*>(&A[(size_t)(rb + r) * 128 + kt * 32 + kq * 8]);
      }
    }
  };

  auto write_tile = [&]() {
#pragma unroll
    for (int it = 0; it < NBIT; ++it) {
      int f = t + it * 256;
      int c = f >> 2, kq = f & 3;
      *reinterpret_cast<int4*>(&Bh[c][kq * 8]) = pbh[it];
      *reinterpret_cast<int4*>(&Bl[c][kq * 8]) = pbl[it];
    }
    if constexpr (ASPLIT) {
#pragma unroll
      for (int j = 0; j < 2; ++j) {
        int f = t + j * 256;
        int r = f >> 3, kq = f & 7;
        float4 v = paf[j];
        ushort4 hv, lv;
        hv.x = f2bf(v.x); hv.y = f2bf(v.y); hv.z = f2bf(v.z); hv.w = f2bf(v.w);
        lv.x = f2bf(v.x - bfval(hv.x)); lv.y = f2bf(v.y - bfval(hv.y));
        lv.z = f2bf(v.z - bfval(hv.z)); lv.w = f2bf(v.w - bfval(hv.w));
        *reinterpret_cast<ushort4*>(&Ah[r][kq * 4]) = hv;
        *reinterpret_cast<ushort4*>(&Al[r][kq * 4]) = lv;
      }
    } else {
#pragma unroll
      for (int j = 0; j < 2; ++j) {
        int f = t + j * 256;
        int r = f >> 2, kq = f & 3;
        *reinterpret_cast<int4*>(&Ah[r][kq * 8]) = pai[j];
      }
    }
  };

  f4v acc[2][4];
#pragma unroll
  for (int i = 0; i < 2; ++i)
#pragma unroll
    for (int j = 0; j < 4; ++j) acc[i][j] = (f4v){0.f, 0.f, 0.f, 0.f};

  load_tile(0);
  write_tile();
  __syncthreads();

  for (int kt = 0; kt < 4; ++kt) {
    if (kt < 3) load_tile(kt + 1);  // issue next-tile loads; latency hides under MFMA

    s8v afh[2], afl[2];
#pragma unroll
    for (int rg = 0; rg < 2; ++rg) {
      afh[rg] = *reinterpret_cast<const s8v*>(&Ah[wr * 32 + rg * 16 + l15][lg * 8]);
      if constexpr (ASPLIT)
        afl[rg] = *reinterpret_cast<const s8v*>(&Al[wr * 32 + rg * 16 + l15][lg * 8]);
    }
#pragma unroll
    for (int cg = 0; cg < 4; ++cg) {
      s8v bh = *reinterpret_cast<const s8v*>(&Bh[wc * 64 + cg * 16 + l15][lg * 8]);
      s8v bl = *reinterpret_cast<const s8v*>(&Bl[wc * 64 + cg * 16 + l15][lg * 8]);
#pragma unroll
      for (int rg = 0; rg < 2; ++rg) {
        acc[rg][cg] = __builtin_amdgcn_mfma_f32_16x16x32_bf16(afh[rg], bh, acc[rg][cg], 0, 0, 0);
        acc[rg][cg] = __builtin_amdgcn_mfma_f32_16x16x32_bf16(afh[rg], bl, acc[rg][cg], 0, 0, 0);
        if constexpr (ASPLIT)
          acc[rg][cg] = __builtin_amdgcn_mfma_f32_16x16x32_bf16(afl[rg], bh, acc[rg][cg], 0, 0, 0);
      }
    }

    if (kt < 3) {
      __syncthreads();  // all waves done reading LDS tile kt
      write_tile();     // waits vmcnt for prefetched regs, converts, writes LDS
      __syncthreads();  // tile kt+1 visible
    }
  }

  // epilogue: scale by dis, store
  float dv[2][4];
#pragma unroll
  for (int rg = 0; rg < 2; ++rg)
#pragma unroll
    for (int g = 0; g < 4; ++g) {
      int r = rb + wr * 32 + rg * 16 + lg * 4 + g;
      dv[rg][g] = (r < M) ? dis[r] : 0.f;
    }
#pragma unroll
  for (int rg = 0; rg < 2; ++rg)
#pragma unroll
    for (int cg = 0; cg < 4; ++cg) {
      int colc = wc * 64 + cg * 16 + l15;
#pragma unroll
      for (int g = 0; g < 4; ++g) {
        int r = rb + wr * 32 + rg * 16 + lg * 4 + g;
        if (r < M) {
          float o = acc[rg][cg][g] * dv[rg][g];
          if constexpr (OUTBF16)
            ((unsigned short*)outv)[(size_t)r * NCOLS + colc] = f2bf(o);
          else
            ((float*)outv)[(size_t)r * NCOLS + colc] = o;
        }
      }
    }
}

// ---------------- Aggregation (unroll 8, 8 independent accumulators) ----------------

__global__ __launch_bounds__(256) void agg_bf16_kernel(
    const unsigned int* __restrict__ H, const int* __restrict__ row_ptr,
    const int* __restrict__ csr, const float* __restrict__ dis,
    const float* __restrict__ bias, unsigned int* __restrict__ Z, int n) {
  const int lane = threadIdx.x & 63;
  const int node = blockIdx.x * 4 + (threadIdx.x >> 6);
  if (node >= n) return;

  float2 a[8];
  a[0] = bfpair(H[(size_t)node * 64 + lane]);  // self-loop
#pragma unroll
  for (int i = 1; i < 8; ++i) a[i] = make_float2(0.f, 0.f);

  const int s0 = row_ptr[node], s1 = row_ptr[node + 1];
  for (int e = s0; e < s1; e += 64) {
    int m = s1 - e;
    if (m > 64) m = 64;
    int idx = 0;
    if (lane < m) idx = csr[e + lane];
    int j = 0;
    for (; j + 8 <= m; j += 8) {
      int i0 = __shfl(idx, j),     i1 = __shfl(idx, j + 1);
      int i2 = __shfl(idx, j + 2), i3 = __shfl(idx, j + 3);
      int i4 = __shfl(idx, j + 4), i5 = __shfl(idx, j + 5);
      int i6 = __shfl(idx, j + 6), i7 = __shfl(idx, j + 7);
      float2 v0 = bfpair(H[(size_t)i0 * 64 + lane]);
      float2 v1 = bfpair(H[(size_t)i1 * 64 + lane]);
      float2 v2 = bfpair(H[(size_t)i2 * 64 + lane]);
      float2 v3 = bfpair(H[(size_t)i3 * 64 + lane]);
      float2 v4 = bfpair(H[(size_t)i4 * 64 + lane]);
      float2 v5 = bfpair(H[(size_t)i5 * 64 + lane]);
      float2 v6 = bfpair(H[(size_t)i6 * 64 + lane]);
      float2 v7 = bfpair(H[(size_t)i7 * 64 + lane]);
      a[0].x += v0.x; a[0].y += v0.y;  a[1].x += v1.x; a[1].y += v1.y;
      a[2].x += v2.x; a[2].y += v2.y;  a[3].x += v3.x; a[3].y += v3.y;
      a[4].x += v4.x; a[4].y += v4.y;  a[5].x += v5.x; a[5].y += v5.y;
      a[6].x += v6.x; a[6].y += v6.y;  a[7].x += v7.x; a[7].y += v7.y;
    }
    for (; j + 4 <= m; j += 4) {
      int i0 = __shfl(idx, j),     i1 = __shfl(idx, j + 1);
      int i2 = __shfl(idx, j + 2), i3 = __shfl(idx, j + 3);
      float2 v0 = bfpair(H[(size_t)i0 * 64 + lane]);
      float2 v1 = bfpair(H[(size_t)i1 * 64 + lane]);
      float2 v2 = bfpair(H[(size_t)i2 * 64 + lane]);
      float2 v3 = bfpair(H[(size_t)i3 * 64 + lane]);
      a[0].x += v0.x; a[0].y += v0.y;  a[1].x += v1.x; a[1].y += v1.y;
      a[2].x += v2.x; a[2].y += v2.y;  a[3].x += v3.x; a[3].y += v3.y;
    }
    for (; j < m; ++j) {
      float2 v = bfpair(H[(size_t)__shfl(idx, j) * 64 + lane]);
      a[0].x += v.x; a[0].y += v.y;
    }
  }
  const float d = dis[node];
  float2 b = *reinterpret_cast<const float2*>(&bias[lane * 2]);
  float sx = ((a[0].x + a[1].x) + (a[2].x + a[3].x)) + ((a[4].x + a[5].x) + (a[6].x + a[7].x));
  float sy = ((a[0].y + a[1].y) + (a[2].y + a[3].y)) + ((a[4].y + a[5].y) + (a[6].y + a[7].y));
  float ox = fmaxf(sx * d + b.x, 0.f);
  float oy = fmaxf(sy * d + b.y, 0.f);
  Z[(size_t)node * 64 + lane] = (unsigned int)f2bf(ox) | ((unsigned int)f2bf(oy) << 16);
}

__global__ __launch_bounds__(256) void agg_f32_kernel(
    const float* __restrict__ Hs, const int* __restrict__ row_ptr,
    const int* __restrict__ csr, const float* __restrict__ dis,
    const float* __restrict__ bias, float* __restrict__ out, int n) {
  const int lane = threadIdx.x & 63;
  const int node = blockIdx.x * 4 + (threadIdx.x >> 6);
  if (node >= n) return;

  float a[8];
  a[0] = Hs[(size_t)node * 64 + lane];  // self-loop
#pragma unroll
  for (int i = 1; i < 8; ++i) a[i] = 0.f;

  const int s0 = row_ptr[node], s1 = row_ptr[node + 1];
  for (int e = s0; e < s1; e += 64) {
    int m = s1 - e;
    if (m > 64) m = 64;
    int idx = 0;
    if (lane < m) idx = csr[e + lane];
    int j = 0;
    for (; j + 8 <= m; j += 8) {
      int i0 = __shfl(idx, j),     i1 = __shfl(idx, j + 1);
      int i2 = __shfl(idx, j + 2), i3 = __shfl(idx, j + 3);
      int i4 = __shfl(idx, j + 4), i5 = __shfl(idx, j + 5);
      int i6 = __shfl(idx, j + 6), i7 = __shfl(idx, j + 7);
      float v0 = Hs[(size_t)i0 * 64 + lane];
      float v1 = Hs[(size_t)i1 * 64 + lane];
      float v2 = Hs[(size_t)i2 * 64 + lane];
      float v3 = Hs[(size_t)i3 * 64 + lane];
      float v4 = Hs[(size_t)i4 * 64 + lane];
      float v5 = Hs[(size_t)i5 * 64 + lane];
      float v6 = Hs[(size_t)i6 * 64 + lane];
      float v7 = Hs[(size_t)i7 * 64 + lane];
      a[0] += v0; a[1] += v1; a[2] += v2; a[3] += v3;
      a[4] += v4; a[5] += v5; a[6] += v6; a[7] += v7;
    }
    for (; j + 4 <= m; j += 4) {
      int i0 = __shfl(idx, j),     i1 = __shfl(idx, j + 1);
      int i2 = __shfl(idx, j + 2), i3 = __shfl(idx, j + 3);
      float v0 = Hs[(size_t)i0 * 64 + lane];
      float v1 = Hs[(size_t)i1 * 64 + lane];
      float v2 = Hs[(size_t)i2 * 64 + lane];
      float v3 = Hs[(size_t)i3 * 64 + lane];
      a[0] += v0; a[1] += v1; a[2] += v2; a[3] += v3;
    }
    for (; j < m; ++j) a[0] += Hs[(size_t)__shfl(idx, j) * 64 + lane];
  }
  float s = ((a[0] + a[1]) + (a[2] + a[3])) + ((a[4] + a[5]) + (a[6] + a[7]));
  out[(size_t)node * 64 + lane] = s * dis[node] + bias[lane];
}

// ---------------- launch ----------------

extern "C" void kernel_launch(void* const* d_in, const int* in_sizes, int n_in,
                              void* d_out, int out_size, void* d_ws, size_t ws_size,
                              hipStream_t stream) {
  const float* x  = (const float*)d_in[0];
  const int*   ei = (const int*)d_in[1];
  const float* W1 = (const float*)d_in[2];
  const float* b1 = (const float*)d_in[3];
  const float* W2 = (const float*)d_in[4];
  const float* b2 = (const float*)d_in[5];
  float* out = (float*)d_out;

  const int* row = ei;        // source nodes
  const int* col = ei + NE;   // destination nodes

  char* ws = (char*)d_ws;
  size_t off = 0;
  auto alloc = [&](size_t bytes) -> void* {
    off = (off + 255) & ~(size_t)255;
    void* p = ws + off;
    off += bytes;
    return p;
  };

  int* cnt     = (int*)alloc((size_t)2 * NN * sizeof(int));  // cnt | fillc
  int* fillc   = cnt + NN;
  int* row_ptr = (int*)alloc((size_t)(NN + 1) * sizeof(int));
  int* csr     = (int*)alloc((size_t)NE * sizeof(int));
  float* dis   = (float*)alloc((size_t)NN * sizeof(float));
  unsigned short* wt1h = (unsigned short*)alloc((size_t)(2 * 128 * 128 + 2 * 64 * 128) * 2);
  unsigned short* wt1l = wt1h + 128 * 128;
  unsigned short* wt2h = wt1l + 128 * 128;
  unsigned short* wt2l = wt2h + 64 * 128;
  // HT region: bf16 [NN][128] for layer-1 GEMM out, then f32 [NN][64] for layer-2
  unsigned short* HT16 = (unsigned short*)alloc((size_t)NN * 128 * 2);
  float* HT32 = (float*)HT16;
  unsigned int* HTu = (unsigned int*)HT16;
  unsigned short* Z1 = (unsigned short*)alloc((size_t)NN * 128 * 2);
  unsigned int* Z1u = (unsigned int*)Z1;

  hipMemsetAsync(cnt, 0, (size_t)2 * NN * sizeof(int), stream);
  wprep_kernel<<<96, 256, 0, stream>>>(W1, W2, wt1h, wt1l, wt2h, wt2l);
  count_kernel<<<NE / 256, 256, 0, stream>>>(col, cnt, NE);
  rowptr_kernel<<<NB, 256, 0, stream>>>(cnt, row_ptr, dis, NN);
  fill_kernel<<<NE / 256, 256, 0, stream>>>(row, col, row_ptr, fillc, csr, NE);

  const int ga = (NN + 3) / 4;

  // Layer 1: HT16 = bf16( dis .* (X @ W1) )  [NN][128]
  gemm_mfma_kernel<128, true, true><<<(NN + 63) / 64, 256, 0, stream>>>(
      x, wt1h, wt1l, dis, HT16, NN);
  agg_bf16_kernel<<<ga, 256, 0, stream>>>(HTu, row_ptr, csr, dis, b1, Z1u, NN);

  // Layer 2: HT32 = dis .* (Z1 @ W2)  [NN][64]
  gemm_mfma_kernel<64, false, false><<<(NN + 127) / 128, 256, 0, stream>>>(
      Z1, wt2h, wt2l, dis, HT32, NN);
  agg_f32_kernel<<<ga, 256, 0, stream>>>(HT32, row_ptr, csr, dis, b2, out, NN);
}

// Round 8
// 163.875 us; speedup vs baseline: 1.1929x; 1.1929x over previous
//
#include <hip/hip_runtime.h>

#define NN 50000
#define NE 640000
#define NB 196  // ceil((NN+1)/256)

typedef __attribute__((ext_vector_type(8))) short s8v;
typedef __attribute__((ext_vector_type(4))) float f4v;

__device__ __forceinline__ unsigned short f2bf(float x) {  // RNE f32->bf16
  unsigned int u = __float_as_uint(x);
  return (unsigned short)((u + 0x7fffu + ((u >> 16) & 1u)) >> 16);
}
__device__ __forceinline__ float bfval(unsigned short h) {
  return __uint_as_float((unsigned int)h << 16);
}
__device__ __forceinline__ float2 bfpair(unsigned int u) {
  float2 r;
  r.x = __uint_as_float((u & 0xffffu) << 16);
  r.y = __uint_as_float(u & 0xffff0000u);
  return r;
}

// ---------------- CSR (dest-keyed) build ----------------

__global__ void count_kernel(const int* __restrict__ col, int* __restrict__ cnt, int n) {
  int i = blockIdx.x * blockDim.x + threadIdx.x;
  if (i < n) atomicAdd(&cnt[col[i]], 1);
}

__global__ __launch_bounds__(256) void block_sum_kernel(const int* __restrict__ cnt,
                                                        int* __restrict__ bsum, int n) {
  __shared__ int ws[4];
  const int tid = threadIdx.x;
  const int t = blockIdx.x * 256 + tid;
  int c = (t < n) ? cnt[t] : 0;
  int s = c;
#pragma unroll
  for (int off = 1; off < 64; off <<= 1) s += __shfl_xor(s, off);
  if ((tid & 63) == 0) ws[tid >> 6] = s;
  __syncthreads();
  if (tid == 0) bsum[blockIdx.x] = ws[0] + ws[1] + ws[2] + ws[3];
}

__global__ __launch_bounds__(256) void scan_bsum_kernel(const int* __restrict__ bsum,
                                                        int* __restrict__ boff, int nb) {
  __shared__ int s[256];
  const int tid = threadIdx.x;
  int v = (tid < nb) ? bsum[tid] : 0;
  s[tid] = v;
  __syncthreads();
  for (int off = 1; off < 256; off <<= 1) {
    int u = (tid >= off) ? s[tid - off] : 0;
    __syncthreads();
    s[tid] += u;
    __syncthreads();
  }
  if (tid < nb) boff[tid] = s[tid] - v;  // exclusive
}

__global__ __launch_bounds__(256) void write_rowptr_kernel(
    const int* __restrict__ cnt, const int* __restrict__ boff,
    int* __restrict__ row_ptr, float* __restrict__ dis, int n) {
  __shared__ int wsum[4];
  const int tid = threadIdx.x;
  const int t = blockIdx.x * 256 + tid;
  const int lane = tid & 63, w = tid >> 6;
  int c = (t < n) ? cnt[t] : 0;
  int inc = c;
#pragma unroll
  for (int off = 1; off < 64; off <<= 1) {
    int u = __shfl_up(inc, off);
    if (lane >= off) inc += u;
  }
  if (lane == 63) wsum[w] = inc;
  __syncthreads();
  int wo = 0;
  for (int i = 0; i < w; ++i) wo += wsum[i];
  int excl = boff[blockIdx.x] + wo + inc - c;
  if (t <= n) row_ptr[t] = excl;
  if (t < n) dis[t] = rsqrtf((float)(c + 1));
}

__global__ void fill_kernel(const int* __restrict__ row, const int* __restrict__ col,
                            const int* __restrict__ row_ptr, int* __restrict__ fillc,
                            int* __restrict__ csr, int n) {
  int i = blockIdx.x * blockDim.x + threadIdx.x;
  if (i < n) {
    int c = col[i];
    int p = row_ptr[c] + atomicAdd(&fillc[c], 1);
    csr[p] = row[i];
  }
}

// ---------------- W prep: transpose + split f32 -> bf16 hi/lo ----------------

__global__ __launch_bounds__(256) void wprep_kernel(
    const float* __restrict__ W1, const float* __restrict__ W2,
    unsigned short* __restrict__ wt1h, unsigned short* __restrict__ wt1l,
    unsigned short* __restrict__ wt2h, unsigned short* __restrict__ wt2l) {
  int idx = blockIdx.x * 256 + threadIdx.x;  // 0..24575
  if (idx < 16384) {
    int c = idx >> 7, k = idx & 127;
    float w = W1[k * 128 + c];
    unsigned short h = f2bf(w);
    wt1h[idx] = h;
    wt1l[idx] = f2bf(w - bfval(h));
  } else if (idx < 24576) {
    int i2 = idx - 16384;
    int c = i2 >> 7, k = i2 & 127;
    float w = W2[k * 64 + c];
    unsigned short h = f2bf(w);
    wt2h[i2] = h;
    wt2l[i2] = f2bf(w - bfval(h));
  }
}

// ---------------- MFMA GEMM (R5-proven single-buffered structure) ----------------
// out[r][c] = dis[r] * sum_{k<128} A[r][k] * Wt[c][k]
// ASPLIT: A is f32, split hi/lo on the fly (3 mfma terms); else A is bf16 (2 terms).
// 256 threads = 4 waves; wave tile 32(M) x 64(N) via 16x16x32 bf16 mfma.
// A-frag: row=lane&15, k=(lane>>4)*8+j ; B-frag: col=lane&15, same k
// C/D: col=lane&15, row=(lane>>4)*4+reg

template <int NCOLS, bool ASPLIT, bool OUTBF16>
__global__ __launch_bounds__(256) void gemm_mfma_kernel(
    const void* __restrict__ Av, const unsigned short* __restrict__ Bth,
    const unsigned short* __restrict__ Btl, const float* __restrict__ dis,
    void* __restrict__ outv, int M) {
  constexpr int WCOL = NCOLS / 64;   // waves along cols
  constexpr int WROW = 4 / WCOL;     // waves along rows
  constexpr int BM = WROW * 32;      // block rows (64 or 128)
  constexpr int P = 40;              // LDS pitch in bf16 (16B-aligned, 2-way free)

  __shared__ unsigned short Ah[BM][P];
  __shared__ unsigned short Al[ASPLIT ? BM : 1][ASPLIT ? P : 1];
  __shared__ unsigned short Bh[NCOLS][P];
  __shared__ unsigned short Bl[NCOLS][P];

  const int t = threadIdx.x;
  const int lane = t & 63;
  const int l15 = lane & 15;
  const int lg = lane >> 4;
  const int wv = t >> 6;
  const int wr = wv % WROW;
  const int wc = wv / WROW;
  const int rb = blockIdx.x * BM;

  f4v acc[2][4];
#pragma unroll
  for (int i = 0; i < 2; ++i)
#pragma unroll
    for (int j = 0; j < 4; ++j) acc[i][j] = (f4v){0.f, 0.f, 0.f, 0.f};

  for (int kt = 0; kt < 4; ++kt) {
    if (kt) __syncthreads();
    // stage B tile [NCOLS][32] hi+lo
#pragma unroll
    for (int f = t; f < NCOLS * 4; f += 256) {
      int c = f >> 2, kq = f & 3;
      *reinterpret_cast<int4*>(&Bh[c][kq * 8]) =
          *reinterpret_cast<const int4*>(&Bth[c * 128 + kt * 32 + kq * 8]);
      *reinterpret_cast<int4*>(&Bl[c][kq * 8]) =
          *reinterpret_cast<const int4*>(&Btl[c * 128 + kt * 32 + kq * 8]);
    }
    // stage A tile [BM][32]
    if constexpr (ASPLIT) {
      const float* A = (const float*)Av;
#pragma unroll
      for (int j = 0; j < 2; ++j) {
        int f = t + j * 256;  // 512 float4 units (BM=64: 64*8)
        int r = f >> 3, kq = f & 7;
        float4 v = make_float4(0.f, 0.f, 0.f, 0.f);
        if (rb + r < M)
          v = *reinterpret_cast<const float4*>(&A[(size_t)(rb + r) * 128 + kt * 32 + kq * 4]);
        ushort4 hv, lv;
        hv.x = f2bf(v.x); hv.y = f2bf(v.y); hv.z = f2bf(v.z); hv.w = f2bf(v.w);
        lv.x = f2bf(v.x - bfval(hv.x)); lv.y = f2bf(v.y - bfval(hv.y));
        lv.z = f2bf(v.z - bfval(hv.z)); lv.w = f2bf(v.w - bfval(hv.w));
        *reinterpret_cast<ushort4*>(&Ah[r][kq * 4]) = hv;
        *reinterpret_cast<ushort4*>(&Al[r][kq * 4]) = lv;
      }
    } else {
      const unsigned short* A = (const unsigned short*)Av;
#pragma unroll
      for (int j = 0; j < 2; ++j) {
        int f = t + j * 256;  // 512 units of 8 bf16 (BM=128: 128*4)
        int r = f >> 2, kq = f & 3;
        int4 v = {0, 0, 0, 0};
        if (rb + r < M)
          v = *reinterpret_cast<const int4*>(&A[(size_t)(rb + r) * 128 + kt * 32 + kq * 8]);
        *reinterpret_cast<int4*>(&Ah[r][kq * 8]) = v;
      }
    }
    __syncthreads();

    s8v afh[2], afl[2];
#pragma unroll
    for (int rg = 0; rg < 2; ++rg) {
      afh[rg] = *reinterpret_cast<const s8v*>(&Ah[wr * 32 + rg * 16 + l15][lg * 8]);
      if constexpr (ASPLIT)
        afl[rg] = *reinterpret_cast<const s8v*>(&Al[wr * 32 + rg * 16 + l15][lg * 8]);
    }
#pragma unroll
    for (int cg = 0; cg < 4; ++cg) {
      s8v bh = *reinterpret_cast<const s8v*>(&Bh[wc * 64 + cg * 16 + l15][lg * 8]);
      s8v bl = *reinterpret_cast<const s8v*>(&Bl[wc * 64 + cg * 16 + l15][lg * 8]);
#pragma unroll
      for (int rg = 0; rg < 2; ++rg) {
        acc[rg][cg] = __builtin_amdgcn_mfma_f32_16x16x32_bf16(afh[rg], bh, acc[rg][cg], 0, 0, 0);
        acc[rg][cg] = __builtin_amdgcn_mfma_f32_16x16x32_bf16(afh[rg], bl, acc[rg][cg], 0, 0, 0);
        if constexpr (ASPLIT)
          acc[rg][cg] = __builtin_amdgcn_mfma_f32_16x16x32_bf16(afl[rg], bh, acc[rg][cg], 0, 0, 0);
      }
    }
  }

  // epilogue: scale by dis, store
  float dv[2][4];
#pragma unroll
  for (int rg = 0; rg < 2; ++rg)
#pragma unroll
    for (int g = 0; g < 4; ++g) {
      int r = rb + wr * 32 + rg * 16 + lg * 4 + g;
      dv[rg][g] = (r < M) ? dis[r] : 0.f;
    }
#pragma unroll
  for (int rg = 0; rg < 2; ++rg)
#pragma unroll
    for (int cg = 0; cg < 4; ++cg) {
      int colc = wc * 64 + cg * 16 + l15;
#pragma unroll
      for (int g = 0; g < 4; ++g) {
        int r = rb + wr * 32 + rg * 16 + lg * 4 + g;
        if (r < M) {
          float o = acc[rg][cg][g] * dv[rg][g];
          if constexpr (OUTBF16)
            ((unsigned short*)outv)[(size_t)r * NCOLS + colc] = f2bf(o);
          else
            ((float*)outv)[(size_t)r * NCOLS + colc] = o;
        }
      }
    }
}

// ---------------- Aggregation (unroll 8, independent accumulators) ----------------

__global__ __launch_bounds__(256) void agg_bf16_kernel(
    const unsigned int* __restrict__ H, const int* __restrict__ row_ptr,
    const int* __restrict__ csr, const float* __restrict__ dis,
    const float* __restrict__ bias, unsigned int* __restrict__ Z, int n) {
  const int lane = threadIdx.x & 63;
  const int node = blockIdx.x * 4 + (threadIdx.x >> 6);
  if (node >= n) return;

  float2 a[8];
  a[0] = bfpair(H[(size_t)node * 64 + lane]);  // self-loop
#pragma unroll
  for (int i = 1; i < 8; ++i) a[i] = make_float2(0.f, 0.f);

  const int s0 = row_ptr[node], s1 = row_ptr[node + 1];
  for (int e = s0; e < s1; e += 64) {
    int m = s1 - e;
    if (m > 64) m = 64;
    int idx = 0;
    if (lane < m) idx = csr[e + lane];
    int j = 0;
    for (; j + 8 <= m; j += 8) {
      int i0 = __shfl(idx, j),     i1 = __shfl(idx, j + 1);
      int i2 = __shfl(idx, j + 2), i3 = __shfl(idx, j + 3);
      int i4 = __shfl(idx, j + 4), i5 = __shfl(idx, j + 5);
      int i6 = __shfl(idx, j + 6), i7 = __shfl(idx, j + 7);
      float2 v0 = bfpair(H[(size_t)i0 * 64 + lane]);
      float2 v1 = bfpair(H[(size_t)i1 * 64 + lane]);
      float2 v2 = bfpair(H[(size_t)i2 * 64 + lane]);
      float2 v3 = bfpair(H[(size_t)i3 * 64 + lane]);
      float2 v4 = bfpair(H[(size_t)i4 * 64 + lane]);
      float2 v5 = bfpair(H[(size_t)i5 * 64 + lane]);
      float2 v6 = bfpair(H[(size_t)i6 * 64 + lane]);
      float2 v7 = bfpair(H[(size_t)i7 * 64 + lane]);
      a[0].x += v0.x; a[0].y += v0.y;  a[1].x += v1.x; a[1].y += v1.y;
      a[2].x += v2.x; a[2].y += v2.y;  a[3].x += v3.x; a[3].y += v3.y;
      a[4].x += v4.x; a[4].y += v4.y;  a[5].x += v5.x; a[5].y += v5.y;
      a[6].x += v6.x; a[6].y += v6.y;  a[7].x += v7.x; a[7].y += v7.y;
    }
    for (; j + 4 <= m; j += 4) {
      int i0 = __shfl(idx, j),     i1 = __shfl(idx, j + 1);
      int i2 = __shfl(idx, j + 2), i3 = __shfl(idx, j + 3);
      float2 v0 = bfpair(H[(size_t)i0 * 64 + lane]);
      float2 v1 = bfpair(H[(size_t)i1 * 64 + lane]);
      float2 v2 = bfpair(H[(size_t)i2 * 64 + lane]);
      float2 v3 = bfpair(H[(size_t)i3 * 64 + lane]);
      a[0].x += v0.x; a[0].y += v0.y;  a[1].x += v1.x; a[1].y += v1.y;
      a[2].x += v2.x; a[2].y += v2.y;  a[3].x += v3.x; a[3].y += v3.y;
    }
    for (; j < m; ++j) {
      float2 v = bfpair(H[(size_t)__shfl(idx, j) * 64 + lane]);
      a[0].x += v.x; a[0].y += v.y;
    }
  }
  const float d = dis[node];
  float2 b = *reinterpret_cast<const float2*>(&bias[lane * 2]);
  float sx = ((a[0].x + a[1].x) + (a[2].x + a[3].x)) + ((a[4].x + a[5].x) + (a[6].x + a[7].x));
  float sy = ((a[0].y + a[1].y) + (a[2].y + a[3].y)) + ((a[4].y + a[5].y) + (a[6].y + a[7].y));
  float ox = fmaxf(sx * d + b.x, 0.f);
  float oy = fmaxf(sy * d + b.y, 0.f);
  Z[(size_t)node * 64 + lane] = (unsigned int)f2bf(ox) | ((unsigned int)f2bf(oy) << 16);
}

__global__ __launch_bounds__(256) void agg_f32_kernel(
    const float* __restrict__ Hs, const int* __restrict__ row_ptr,
    const int* __restrict__ csr, const float* __restrict__ dis,
    const float* __restrict__ bias, float* __restrict__ out, int n) {
  const int lane = threadIdx.x & 63;
  const int node = blockIdx.x * 4 + (threadIdx.x >> 6);
  if (node >= n) return;

  float a[8];
  a[0] = Hs[(size_t)node * 64 + lane];  // self-loop
#pragma unroll
  for (int i = 1; i < 8; ++i) a[i] = 0.f;

  const int s0 = row_ptr[node], s1 = row_ptr[node + 1];
  for (int e = s0; e < s1; e += 64) {
    int m = s1 - e;
    if (m > 64) m = 64;
    int idx = 0;
    if (lane < m) idx = csr[e + lane];
    int j = 0;
    for (; j + 8 <= m; j += 8) {
      int i0 = __shfl(idx, j),     i1 = __shfl(idx, j + 1);
      int i2 = __shfl(idx, j + 2), i3 = __shfl(idx, j + 3);
      int i4 = __shfl(idx, j + 4), i5 = __shfl(idx, j + 5);
      int i6 = __shfl(idx, j + 6), i7 = __shfl(idx, j + 7);
      float v0 = Hs[(size_t)i0 * 64 + lane];
      float v1 = Hs[(size_t)i1 * 64 + lane];
      float v2 = Hs[(size_t)i2 * 64 + lane];
      float v3 = Hs[(size_t)i3 * 64 + lane];
      float v4 = Hs[(size_t)i4 * 64 + lane];
      float v5 = Hs[(size_t)i5 * 64 + lane];
      float v6 = Hs[(size_t)i6 * 64 + lane];
      float v7 = Hs[(size_t)i7 * 64 + lane];
      a[0] += v0; a[1] += v1; a[2] += v2; a[3] += v3;
      a[4] += v4; a[5] += v5; a[6] += v6; a[7] += v7;
    }
    for (; j + 4 <= m; j += 4) {
      int i0 = __shfl(idx, j),     i1 = __shfl(idx, j + 1);
      int i2 = __shfl(idx, j + 2), i3 = __shfl(idx, j + 3);
      float v0 = Hs[(size_t)i0 * 64 + lane];
      float v1 = Hs[(size_t)i1 * 64 + lane];
      float v2 = Hs[(size_t)i2 * 64 + lane];
      float v3 = Hs[(size_t)i3 * 64 + lane];
      a[0] += v0; a[1] += v1; a[2] += v2; a[3] += v3;
    }
    for (; j < m; ++j) a[0] += Hs[(size_t)__shfl(idx, j) * 64 + lane];
  }
  float s = ((a[0] + a[1]) + (a[2] + a[3])) + ((a[4] + a[5]) + (a[6] + a[7]));
  out[(size_t)node * 64 + lane] = s * dis[node] + bias[lane];
}

// ---------------- launch ----------------

extern "C" void kernel_launch(void* const* d_in, const int* in_sizes, int n_in,
                              void* d_out, int out_size, void* d_ws, size_t ws_size,
                              hipStream_t stream) {
  const float* x  = (const float*)d_in[0];
  const int*   ei = (const int*)d_in[1];
  const float* W1 = (const float*)d_in[2];
  const float* b1 = (const float*)d_in[3];
  const float* W2 = (const float*)d_in[4];
  const float* b2 = (const float*)d_in[5];
  float* out = (float*)d_out;

  const int* row = ei;        // source nodes
  const int* col = ei + NE;   // destination nodes

  char* ws = (char*)d_ws;
  size_t off = 0;
  auto alloc = [&](size_t bytes) -> void* {
    off = (off + 255) & ~(size_t)255;
    void* p = ws + off;
    off += bytes;
    return p;
  };

  int* cnt     = (int*)alloc((size_t)2 * NN * sizeof(int));  // cnt | fillc
  int* fillc   = cnt + NN;
  int* row_ptr = (int*)alloc((size_t)(NN + 1) * sizeof(int));
  int* csr     = (int*)alloc((size_t)NE * sizeof(int));
  float* dis   = (float*)alloc((size_t)NN * sizeof(float));
  int* bsum    = (int*)alloc((size_t)NB * sizeof(int));
  int* boff    = (int*)alloc((size_t)NB * sizeof(int));
  unsigned short* wt1h = (unsigned short*)alloc((size_t)(2 * 128 * 128 + 2 * 64 * 128) * 2);
  unsigned short* wt1l = wt1h + 128 * 128;
  unsigned short* wt2h = wt1l + 128 * 128;
  unsigned short* wt2l = wt2h + 64 * 128;
  // HT region: bf16 [NN][128] for layer-1 GEMM out, then f32 [NN][64] for layer-2
  unsigned short* HT16 = (unsigned short*)alloc((size_t)NN * 128 * 2);
  float* HT32 = (float*)HT16;
  unsigned int* HTu = (unsigned int*)HT16;
  unsigned short* Z1 = (unsigned short*)alloc((size_t)NN * 128 * 2);
  unsigned int* Z1u = (unsigned int*)Z1;

  hipMemsetAsync(cnt, 0, (size_t)2 * NN * sizeof(int), stream);
  wprep_kernel<<<96, 256, 0, stream>>>(W1, W2, wt1h, wt1l, wt2h, wt2l);
  count_kernel<<<NE / 256, 256, 0, stream>>>(col, cnt, NE);
  block_sum_kernel<<<NB, 256, 0, stream>>>(cnt, bsum, NN);
  scan_bsum_kernel<<<1, 256, 0, stream>>>(bsum, boff, NB);
  write_rowptr_kernel<<<NB, 256, 0, stream>>>(cnt, boff, row_ptr, dis, NN);
  fill_kernel<<<NE / 256, 256, 0, stream>>>(row, col, row_ptr, fillc, csr, NE);

  const int ga = (NN + 3) / 4;

  // Layer 1: HT16 = bf16( dis .* (X @ W1) )  [NN][128]
  gemm_mfma_kernel<128, true, true><<<(NN + 63) / 64, 256, 0, stream>>>(
      x, wt1h, wt1l, dis, HT16, NN);
  agg_bf16_kernel<<<ga, 256, 0, stream>>>(HTu, row_ptr, csr, dis, b1, Z1u, NN);

  // Layer 2: HT32 = dis .* (Z1 @ W2)  [NN][64]
  gemm_mfma_kernel<64, false, false><<<(NN + 127) / 128, 256, 0, stream>>>(
      Z1, wt2h, wt2l, dis, HT32, NN);
  agg_f32_kernel<<<ga, 256, 0, stream>>>(HT32, row_ptr, csr, dis, b2, out, NN);
}

// Round 9
// 128.590 us; speedup vs baseline: 1.5202x; 1.2744x over previous
//
#include <hip/hip_runtime.h>

#define NN 50000
#define NE 640000
#define NBK 196      // buckets of 256 nodes: ceil(50000/256)
#define CHUNK 2560   // edges per block in bucket passes: NE/CHUNK = 250 exactly

typedef __attribute__((ext_vector_type(8))) short s8v;
typedef __attribute__((ext_vector_type(4))) float f4v;

__device__ __forceinline__ unsigned short f2bf(float x) {  // RNE f32->bf16
  unsigned int u = __float_as_uint(x);
  return (unsigned short)((u + 0x7fffu + ((u >> 16) & 1u)) >> 16);
}
__device__ __forceinline__ float bfval(unsigned short h) {
  return __uint_as_float((unsigned int)h << 16);
}
__device__ __forceinline__ float2 bfpair(unsigned int u) {
  float2 r;
  r.x = __uint_as_float((u & 0xffffu) << 16);
  r.y = __uint_as_float(u & 0xffff0000u);
  return r;
}

// ---------------- Bucketed CSR (dest-keyed) build ----------------
// All global writes are dense/contiguous per block -> no cross-XCD false sharing.

__global__ __launch_bounds__(256) void bucket_count_kernel(const int* __restrict__ col,
                                                           int* __restrict__ bcnt) {
  __shared__ int h[NBK];
  const int tid = threadIdx.x;
  for (int i = tid; i < NBK; i += 256) h[i] = 0;
  __syncthreads();
  const int base = blockIdx.x * CHUNK;
  for (int i = tid; i < CHUNK; i += 256) atomicAdd(&h[col[base + i] >> 8], 1);
  __syncthreads();
  for (int i = tid; i < NBK; i += 256)
    if (h[i]) atomicAdd(&bcnt[i], h[i]);
}

__global__ __launch_bounds__(256) void scan196_kernel(const int* __restrict__ bcnt,
                                                      int* __restrict__ boff) {
  __shared__ int s[256];
  const int tid = threadIdx.x;
  int v = (tid < NBK) ? bcnt[tid] : 0;
  s[tid] = v;
  __syncthreads();
  for (int off = 1; off < 256; off <<= 1) {
    int u = (tid >= off) ? s[tid - off] : 0;
    __syncthreads();
    s[tid] += u;
    __syncthreads();
  }
  if (tid <= NBK) boff[tid] = (tid == 0) ? 0 : s[tid - 1];  // exclusive; boff[NBK]=NE
}

__global__ __launch_bounds__(256) void bucket_scatter_kernel(
    const int* __restrict__ row, const int* __restrict__ col,
    const int* __restrict__ boff, int* __restrict__ bfill,
    unsigned int* __restrict__ ebuf) {
  __shared__ int h[NBK], gst[NBK], h2[NBK];
  const int tid = threadIdx.x;
  for (int i = tid; i < NBK; i += 256) { h[i] = 0; h2[i] = 0; }
  __syncthreads();
  const int base = blockIdx.x * CHUNK;
  for (int i = tid; i < CHUNK; i += 256) atomicAdd(&h[col[base + i] >> 8], 1);
  __syncthreads();
  for (int i = tid; i < NBK; i += 256) gst[i] = h[i] ? atomicAdd(&bfill[i], h[i]) : 0;
  __syncthreads();
  for (int i = tid; i < CHUNK; i += 256) {
    int c = col[base + i];
    int b = c >> 8;
    int r = atomicAdd(&h2[b], 1);
    unsigned int packed = ((unsigned int)row[base + i] << 8) | (unsigned int)(c & 255);
    ebuf[boff[b] + gst[b] + r] = packed;  // contiguous run per (block,bucket)
  }
}

// One block per bucket: per-node counts -> row_ptr slice + dis + bucket-local csr.
__global__ __launch_bounds__(256) void bucket_build_kernel(
    const unsigned int* __restrict__ ebuf, const int* __restrict__ boff,
    int* __restrict__ row_ptr, float* __restrict__ dis, int* __restrict__ csr, int n) {
  __shared__ int cnt[256], c2[256], lbase[256], wsum[4];
  const int tid = threadIdx.x;
  const int b = blockIdx.x;
  const int s0 = boff[b], s1 = boff[b + 1];
  cnt[tid] = 0;
  c2[tid] = 0;
  __syncthreads();
  for (int i = s0 + tid; i < s1; i += 256) atomicAdd(&cnt[ebuf[i] & 255], 1);
  __syncthreads();

  // block exclusive scan of cnt (wave shuffle + wave sums)
  const int lane = tid & 63, w = tid >> 6;
  int c = cnt[tid];
  int inc = c;
#pragma unroll
  for (int off = 1; off < 64; off <<= 1) {
    int u = __shfl_up(inc, off);
    if (lane >= off) inc += u;
  }
  if (lane == 63) wsum[w] = inc;
  __syncthreads();
  int wo = 0;
  for (int i = 0; i < w; ++i) wo += wsum[i];
  const int excl = wo + inc - c;

  const int node = b * 256 + tid;
  if (node <= n) row_ptr[node] = s0 + excl;  // node==n lands here with c==0 -> NE
  if (node < n) dis[node] = rsqrtf((float)(c + 1));
  lbase[tid] = s0 + excl;
  __syncthreads();

  for (int i = s0 + tid; i < s1; i += 256) {
    unsigned int p = ebuf[i];
    int dl = p & 255;
    int r = atomicAdd(&c2[dl], 1);
    csr[lbase[dl] + r] = (int)(p >> 8);  // writes confined to this bucket's region
  }
}

// ---------------- W prep: transpose + split f32 -> bf16 hi/lo ----------------

__global__ __launch_bounds__(256) void wprep_kernel(
    const float* __restrict__ W1, const float* __restrict__ W2,
    unsigned short* __restrict__ wt1h, unsigned short* __restrict__ wt1l,
    unsigned short* __restrict__ wt2h, unsigned short* __restrict__ wt2l) {
  int idx = blockIdx.x * 256 + threadIdx.x;  // 0..24575
  if (idx < 16384) {
    int c = idx >> 7, k = idx & 127;
    float w = W1[k * 128 + c];
    unsigned short h = f2bf(w);
    wt1h[idx] = h;
    wt1l[idx] = f2bf(w - bfval(h));
  } else if (idx < 24576) {
    int i2 = idx - 16384;
    int c = i2 >> 7, k = i2 & 127;
    float w = W2[k * 64 + c];
    unsigned short h = f2bf(w);
    wt2h[i2] = h;
    wt2l[i2] = f2bf(w - bfval(h));
  }
}

// ---------------- MFMA GEMM (R5-proven single-buffered structure) ----------------

template <int NCOLS, bool ASPLIT, bool OUTBF16>
__global__ __launch_bounds__(256) void gemm_mfma_kernel(
    const void* __restrict__ Av, const unsigned short* __restrict__ Bth,
    const unsigned short* __restrict__ Btl, const float* __restrict__ dis,
    void* __restrict__ outv, int M) {
  constexpr int WCOL = NCOLS / 64;   // waves along cols
  constexpr int WROW = 4 / WCOL;     // waves along rows
  constexpr int BM = WROW * 32;      // block rows (64 or 128)
  constexpr int P = 40;              // LDS pitch in bf16

  __shared__ unsigned short Ah[BM][P];
  __shared__ unsigned short Al[ASPLIT ? BM : 1][ASPLIT ? P : 1];
  __shared__ unsigned short Bh[NCOLS][P];
  __shared__ unsigned short Bl[NCOLS][P];

  const int t = threadIdx.x;
  const int lane = t & 63;
  const int l15 = lane & 15;
  const int lg = lane >> 4;
  const int wv = t >> 6;
  const int wr = wv % WROW;
  const int wc = wv / WROW;
  const int rb = blockIdx.x * BM;

  f4v acc[2][4];
#pragma unroll
  for (int i = 0; i < 2; ++i)
#pragma unroll
    for (int j = 0; j < 4; ++j) acc[i][j] = (f4v){0.f, 0.f, 0.f, 0.f};

  for (int kt = 0; kt < 4; ++kt) {
    if (kt) __syncthreads();
#pragma unroll
    for (int f = t; f < NCOLS * 4; f += 256) {
      int c = f >> 2, kq = f & 3;
      *reinterpret_cast<int4*>(&Bh[c][kq * 8]) =
          *reinterpret_cast<const int4*>(&Bth[c * 128 + kt * 32 + kq * 8]);
      *reinterpret_cast<int4*>(&Bl[c][kq * 8]) =
          *reinterpret_cast<const int4*>(&Btl[c * 128 + kt * 32 + kq * 8]);
    }
    if constexpr (ASPLIT) {
      const float* A = (const float*)Av;
#pragma unroll
      for (int j = 0; j < 2; ++j) {
        int f = t + j * 256;
        int r = f >> 3, kq = f & 7;
        float4 v = make_float4(0.f, 0.f, 0.f, 0.f);
        if (rb + r < M)
          v = *reinterpret_cast<const float4*>(&A[(size_t)(rb + r) * 128 + kt * 32 + kq * 4]);
        ushort4 hv, lv;
        hv.x = f2bf(v.x); hv.y = f2bf(v.y); hv.z = f2bf(v.z); hv.w = f2bf(v.w);
        lv.x = f2bf(v.x - bfval(hv.x)); lv.y = f2bf(v.y - bfval(hv.y));
        lv.z = f2bf(v.z - bfval(hv.z)); lv.w = f2bf(v.w - bfval(hv.w));
        *reinterpret_cast<ushort4*>(&Ah[r][kq * 4]) = hv;
        *reinterpret_cast<ushort4*>(&Al[r][kq * 4]) = lv;
      }
    } else {
      const unsigned short* A = (const unsigned short*)Av;
#pragma unroll
      for (int j = 0; j < 2; ++j) {
        int f = t + j * 256;
        int r = f >> 2, kq = f & 3;
        int4 v = {0, 0, 0, 0};
        if (rb + r < M)
          v = *reinterpret_cast<const int4*>(&A[(size_t)(rb + r) * 128 + kt * 32 + kq * 8]);
        *reinterpret_cast<int4*>(&Ah[r][kq * 8]) = v;
      }
    }
    __syncthreads();

    s8v afh[2], afl[2];
#pragma unroll
    for (int rg = 0; rg < 2; ++rg) {
      afh[rg] = *reinterpret_cast<const s8v*>(&Ah[wr * 32 + rg * 16 + l15][lg * 8]);
      if constexpr (ASPLIT)
        afl[rg] = *reinterpret_cast<const s8v*>(&Al[wr * 32 + rg * 16 + l15][lg * 8]);
    }
#pragma unroll
    for (int cg = 0; cg < 4; ++cg) {
      s8v bh = *reinterpret_cast<const s8v*>(&Bh[wc * 64 + cg * 16 + l15][lg * 8]);
      s8v bl = *reinterpret_cast<const s8v*>(&Bl[wc * 64 + cg * 16 + l15][lg * 8]);
#pragma unroll
      for (int rg = 0; rg < 2; ++rg) {
        acc[rg][cg] = __builtin_amdgcn_mfma_f32_16x16x32_bf16(afh[rg], bh, acc[rg][cg], 0, 0, 0);
        acc[rg][cg] = __builtin_amdgcn_mfma_f32_16x16x32_bf16(afh[rg], bl, acc[rg][cg], 0, 0, 0);
        if constexpr (ASPLIT)
          acc[rg][cg] = __builtin_amdgcn_mfma_f32_16x16x32_bf16(afl[rg], bh, acc[rg][cg], 0, 0, 0);
      }
    }
  }

  float dv[2][4];
#pragma unroll
  for (int rg = 0; rg < 2; ++rg)
#pragma unroll
    for (int g = 0; g < 4; ++g) {
      int r = rb + wr * 32 + rg * 16 + lg * 4 + g;
      dv[rg][g] = (r < M) ? dis[r] : 0.f;
    }
#pragma unroll
  for (int rg = 0; rg < 2; ++rg)
#pragma unroll
    for (int cg = 0; cg < 4; ++cg) {
      int colc = wc * 64 + cg * 16 + l15;
#pragma unroll
      for (int g = 0; g < 4; ++g) {
        int r = rb + wr * 32 + rg * 16 + lg * 4 + g;
        if (r < M) {
          float o = acc[rg][cg][g] * dv[rg][g];
          if constexpr (OUTBF16)
            ((unsigned short*)outv)[(size_t)r * NCOLS + colc] = f2bf(o);
          else
            ((float*)outv)[(size_t)r * NCOLS + colc] = o;
        }
      }
    }
}

// ---------------- Aggregation (unroll 8, independent accumulators) ----------------

__global__ __launch_bounds__(256) void agg_bf16_kernel(
    const unsigned int* __restrict__ H, const int* __restrict__ row_ptr,
    const int* __restrict__ csr, const float* __restrict__ dis,
    const float* __restrict__ bias, unsigned int* __restrict__ Z, int n) {
  const int lane = threadIdx.x & 63;
  const int node = blockIdx.x * 4 + (threadIdx.x >> 6);
  if (node >= n) return;

  float2 a[8];
  a[0] = bfpair(H[(size_t)node * 64 + lane]);  // self-loop
#pragma unroll
  for (int i = 1; i < 8; ++i) a[i] = make_float2(0.f, 0.f);

  const int s0 = row_ptr[node], s1 = row_ptr[node + 1];
  for (int e = s0; e < s1; e += 64) {
    int m = s1 - e;
    if (m > 64) m = 64;
    int idx = 0;
    if (lane < m) idx = csr[e + lane];
    int j = 0;
    for (; j + 8 <= m; j += 8) {
      int i0 = __shfl(idx, j),     i1 = __shfl(idx, j + 1);
      int i2 = __shfl(idx, j + 2), i3 = __shfl(idx, j + 3);
      int i4 = __shfl(idx, j + 4), i5 = __shfl(idx, j + 5);
      int i6 = __shfl(idx, j + 6), i7 = __shfl(idx, j + 7);
      float2 v0 = bfpair(H[(size_t)i0 * 64 + lane]);
      float2 v1 = bfpair(H[(size_t)i1 * 64 + lane]);
      float2 v2 = bfpair(H[(size_t)i2 * 64 + lane]);
      float2 v3 = bfpair(H[(size_t)i3 * 64 + lane]);
      float2 v4 = bfpair(H[(size_t)i4 * 64 + lane]);
      float2 v5 = bfpair(H[(size_t)i5 * 64 + lane]);
      float2 v6 = bfpair(H[(size_t)i6 * 64 + lane]);
      float2 v7 = bfpair(H[(size_t)i7 * 64 + lane]);
      a[0].x += v0.x; a[0].y += v0.y;  a[1].x += v1.x; a[1].y += v1.y;
      a[2].x += v2.x; a[2].y += v2.y;  a[3].x += v3.x; a[3].y += v3.y;
      a[4].x += v4.x; a[4].y += v4.y;  a[5].x += v5.x; a[5].y += v5.y;
      a[6].x += v6.x; a[6].y += v6.y;  a[7].x += v7.x; a[7].y += v7.y;
    }
    for (; j + 4 <= m; j += 4) {
      int i0 = __shfl(idx, j),     i1 = __shfl(idx, j + 1);
      int i2 = __shfl(idx, j + 2), i3 = __shfl(idx, j + 3);
      float2 v0 = bfpair(H[(size_t)i0 * 64 + lane]);
      float2 v1 = bfpair(H[(size_t)i1 * 64 + lane]);
      float2 v2 = bfpair(H[(size_t)i2 * 64 + lane]);
      float2 v3 = bfpair(H[(size_t)i3 * 64 + lane]);
      a[0].x += v0.x; a[0].y += v0.y;  a[1].x += v1.x; a[1].y += v1.y;
      a[2].x += v2.x; a[2].y += v2.y;  a[3].x += v3.x; a[3].y += v3.y;
    }
    for (; j < m; ++j) {
      float2 v = bfpair(H[(size_t)__shfl(idx, j) * 64 + lane]);
      a[0].x += v.x; a[0].y += v.y;
    }
  }
  const float d = dis[node];
  float2 b = *reinterpret_cast<const float2*>(&bias[lane * 2]);
  float sx = ((a[0].x + a[1].x) + (a[2].x + a[3].x)) + ((a[4].x + a[5].x) + (a[6].x + a[7].x));
  float sy = ((a[0].y + a[1].y) + (a[2].y + a[3].y)) + ((a[4].y + a[5].y) + (a[6].y + a[7].y));
  float ox = fmaxf(sx * d + b.x, 0.f);
  float oy = fmaxf(sy * d + b.y, 0.f);
  Z[(size_t)node * 64 + lane] = (unsigned int)f2bf(ox) | ((unsigned int)f2bf(oy) << 16);
}

__global__ __launch_bounds__(256) void agg_f32_kernel(
    const float* __restrict__ Hs, const int* __restrict__ row_ptr,
    const int* __restrict__ csr, const float* __restrict__ dis,
    const float* __restrict__ bias, float* __restrict__ out, int n) {
  const int lane = threadIdx.x & 63;
  const int node = blockIdx.x * 4 + (threadIdx.x >> 6);
  if (node >= n) return;

  float a[8];
  a[0] = Hs[(size_t)node * 64 + lane];  // self-loop
#pragma unroll
  for (int i = 1; i < 8; ++i) a[i] = 0.f;

  const int s0 = row_ptr[node], s1 = row_ptr[node + 1];
  for (int e = s0; e < s1; e += 64) {
    int m = s1 - e;
    if (m > 64) m = 64;
    int idx = 0;
    if (lane < m) idx = csr[e + lane];
    int j = 0;
    for (; j + 8 <= m; j += 8) {
      int i0 = __shfl(idx, j),     i1 = __shfl(idx, j + 1);
      int i2 = __shfl(idx, j + 2), i3 = __shfl(idx, j + 3);
      int i4 = __shfl(idx, j + 4), i5 = __shfl(idx, j + 5);
      int i6 = __shfl(idx, j + 6), i7 = __shfl(idx, j + 7);
      float v0 = Hs[(size_t)i0 * 64 + lane];
      float v1 = Hs[(size_t)i1 * 64 + lane];
      float v2 = Hs[(size_t)i2 * 64 + lane];
      float v3 = Hs[(size_t)i3 * 64 + lane];
      float v4 = Hs[(size_t)i4 * 64 + lane];
      float v5 = Hs[(size_t)i5 * 64 + lane];
      float v6 = Hs[(size_t)i6 * 64 + lane];
      float v7 = Hs[(size_t)i7 * 64 + lane];
      a[0] += v0; a[1] += v1; a[2] += v2; a[3] += v3;
      a[4] += v4; a[5] += v5; a[6] += v6; a[7] += v7;
    }
    for (; j + 4 <= m; j += 4) {
      int i0 = __shfl(idx, j),     i1 = __shfl(idx, j + 1);
      int i2 = __shfl(idx, j + 2), i3 = __shfl(idx, j + 3);
      float v0 = Hs[(size_t)i0 * 64 + lane];
      float v1 = Hs[(size_t)i1 * 64 + lane];
      float v2 = Hs[(size_t)i2 * 64 + lane];
      float v3 = Hs[(size_t)i3 * 64 + lane];
      a[0] += v0; a[1] += v1; a[2] += v2; a[3] += v3;
    }
    for (; j < m; ++j) a[0] += Hs[(size_t)__shfl(idx, j) * 64 + lane];
  }
  float s = ((a[0] + a[1]) + (a[2] + a[3])) + ((a[4] + a[5]) + (a[6] + a[7]));
  out[(size_t)node * 64 + lane] = s * dis[node] + bias[lane];
}

// ---------------- launch ----------------

extern "C" void kernel_launch(void* const* d_in, const int* in_sizes, int n_in,
                              void* d_out, int out_size, void* d_ws, size_t ws_size,
                              hipStream_t stream) {
  const float* x  = (const float*)d_in[0];
  const int*   ei = (const int*)d_in[1];
  const float* W1 = (const float*)d_in[2];
  const float* b1 = (const float*)d_in[3];
  const float* W2 = (const float*)d_in[4];
  const float* b2 = (const float*)d_in[5];
  float* out = (float*)d_out;

  const int* row = ei;        // source nodes
  const int* col = ei + NE;   // destination nodes

  char* ws = (char*)d_ws;
  size_t off = 0;
  auto alloc = [&](size_t bytes) -> void* {
    off = (off + 255) & ~(size_t)255;
    void* p = ws + off;
    off += bytes;
    return p;
  };

  int* bcnt    = (int*)alloc((size_t)2 * NBK * sizeof(int));  // bcnt | bfill contiguous
  int* bfill   = bcnt + NBK;
  int* boff    = (int*)alloc((size_t)(NBK + 1) * sizeof(int));
  unsigned int* ebuf = (unsigned int*)alloc((size_t)NE * sizeof(unsigned int));
  int* row_ptr = (int*)alloc((size_t)(NN + 1) * sizeof(int));
  int* csr     = (int*)alloc((size_t)NE * sizeof(int));
  float* dis   = (float*)alloc((size_t)NN * sizeof(float));
  unsigned short* wt1h = (unsigned short*)alloc((size_t)(2 * 128 * 128 + 2 * 64 * 128) * 2);
  unsigned short* wt1l = wt1h + 128 * 128;
  unsigned short* wt2h = wt1l + 128 * 128;
  unsigned short* wt2l = wt2h + 64 * 128;
  // HT region: bf16 [NN][128] for layer-1 GEMM out, then f32 [NN][64] for layer-2
  unsigned short* HT16 = (unsigned short*)alloc((size_t)NN * 128 * 2);
  float* HT32 = (float*)HT16;
  unsigned int* HTu = (unsigned int*)HT16;
  unsigned short* Z1 = (unsigned short*)alloc((size_t)NN * 128 * 2);
  unsigned int* Z1u = (unsigned int*)Z1;

  hipMemsetAsync(bcnt, 0, (size_t)2 * NBK * sizeof(int), stream);
  wprep_kernel<<<96, 256, 0, stream>>>(W1, W2, wt1h, wt1l, wt2h, wt2l);
  bucket_count_kernel<<<NE / CHUNK, 256, 0, stream>>>(col, bcnt);
  scan196_kernel<<<1, 256, 0, stream>>>(bcnt, boff);
  bucket_scatter_kernel<<<NE / CHUNK, 256, 0, stream>>>(row, col, boff, bfill, ebuf);
  bucket_build_kernel<<<NBK, 256, 0, stream>>>(ebuf, boff, row_ptr, dis, csr, NN);

  const int ga = (NN + 3) / 4;

  // Layer 1: HT16 = bf16( dis .* (X @ W1) )  [NN][128]
  gemm_mfma_kernel<128, true, true><<<(NN + 63) / 64, 256, 0, stream>>>(
      x, wt1h, wt1l, dis, HT16, NN);
  agg_bf16_kernel<<<ga, 256, 0, stream>>>(HTu, row_ptr, csr, dis, b1, Z1u, NN);

  // Layer 2: HT32 = dis .* (Z1 @ W2)  [NN][64]
  gemm_mfma_kernel<64, false, false><<<(NN + 127) / 128, 256, 0, stream>>>(
      Z1, wt2h, wt2l, dis, HT32, NN);
  agg_f32_kernel<<<ga, 256, 0, stream>>>(HT32, row_ptr, csr, dis, b2, out, NN);
}